// Round 6
// baseline (674.281 us; speedup 1.0000x reference)
//
#include <hip/hip_runtime.h>
#include <hip/hip_fp16.h>

#define T_ 2048
#define C_ 2048
#define H_ 128
#define E_ 16
#define N_TOK 8192
#define NS_ 4
#define SCALE_ 0.08838834764831845f   // 1/sqrt(128)

typedef _Float16 f16;
typedef _Float16 f16x4 __attribute__((ext_vector_type(4)));
typedef _Float16 f16x8 __attribute__((ext_vector_type(8)));
typedef float f32x4 __attribute__((ext_vector_type(4)));
typedef unsigned int u32x4 __attribute__((ext_vector_type(4)));

#define MFMA(a,b,c) __builtin_amdgcn_mfma_f32_16x16x32_f16(a,b,c,0,0,0)

__device__ __forceinline__ void gload16(const void* g, void* l){
  __builtin_amdgcn_global_load_lds(
      (const __attribute__((address_space(1))) unsigned int*)g,
      (__attribute__((address_space(3))) unsigned int*)l, 16, 0, 0);
}

// ------------------------------------------------------------------
// prep: column norms of sim_matrix (inverse, f64), sigmoid(gates)
// ------------------------------------------------------------------
__global__ __launch_bounds__(256) void prep_kernel(const float* __restrict__ sim,
    const float* __restrict__ gates, double* __restrict__ wninv, double* __restrict__ sigg){
  __shared__ double part[16][17];
  int tid = threadIdx.x;
  int col = tid & 15, grp = tid >> 4;
  double ssq = 0.0;
  for (int r = grp; r < C_; r += 16){ float v = sim[r*E_ + col]; ssq += (double)v*(double)v; }
  part[grp][col] = ssq;
  __syncthreads();
  if (tid < E_){
    double s = 0.0;
    #pragma unroll
    for (int g2 = 0; g2 < 16; g2++) s += part[g2][tid];
    wninv[tid] = 1.0 / fmax(sqrt(s), 1e-12);
    sigg[tid]  = 1.0 / (1.0 + exp(-(double)gates[tid]));
  }
}

// ------------------------------------------------------------------
// converts: x -> f16; q/k/v_proj -> f16 transposed [e][384][2048];
// o_proj -> f16 transposed [e][2048][128]
// ------------------------------------------------------------------
__global__ __launch_bounds__(256) void conv_x(const float* __restrict__ x, f16* __restrict__ xh){
  for (int v = blockIdx.x*256 + threadIdx.x; v < N_TOK*C_/4; v += 4096*256){
    f32x4 a = *(const f32x4*)&x[(size_t)v*4];
    f16x4 h; h[0]=(f16)a[0]; h[1]=(f16)a[1]; h[2]=(f16)a[2]; h[3]=(f16)a[3];
    *(f16x4*)&xh[(size_t)v*4] = h;
  }
}

__global__ __launch_bounds__(256) void conv_w(const float* __restrict__ qp,
    const float* __restrict__ kp, const float* __restrict__ vp, f16* __restrict__ wT){
  int ep = blockIdx.z; int e = ep/3, proj = ep - 3*e;
  const float* W = (proj==0?qp:(proj==1?kp:vp)) + (size_t)e*C_*H_;
  int k0 = blockIdx.x*64, j0 = blockIdx.y*64;
  __shared__ float t[64][65];
  int tid = threadIdx.x;
  #pragma unroll
  for (int i = 0; i < 4; i++){
    int s = tid + 256*i;
    int r = s >> 4, c4 = (s & 15)*4;
    f32x4 a = *(const f32x4*)&W[(size_t)(k0+r)*H_ + j0 + c4];
    t[r][c4]=a[0]; t[r][c4+1]=a[1]; t[r][c4+2]=a[2]; t[r][c4+3]=a[3];
  }
  __syncthreads();
  #pragma unroll
  for (int i = 0; i < 4; i++){
    int s = tid + 256*i;
    int jj = s >> 4, k4 = (s & 15)*4;
    f16x4 h;
    h[0]=(f16)t[k4][jj]; h[1]=(f16)t[k4+1][jj]; h[2]=(f16)t[k4+2][jj]; h[3]=(f16)t[k4+3][jj];
    *(f16x4*)&wT[((size_t)e*384 + proj*128 + j0 + jj)*C_ + k0 + k4] = h;
  }
}

__global__ __launch_bounds__(256) void conv_o(const float* __restrict__ op, f16* __restrict__ oT){
  int e = blockIdx.z;
  int n0 = blockIdx.x*64, k0 = blockIdx.y*64;
  __shared__ float t[64][65];
  int tid = threadIdx.x;
  #pragma unroll
  for (int i = 0; i < 4; i++){
    int s = tid + 256*i;
    int r = s >> 4, c4 = (s & 15)*4;   // r: k, c4: n
    f32x4 a = *(const f32x4*)&op[(size_t)e*H_*C_ + (size_t)(k0+r)*C_ + n0 + c4];
    t[r][c4]=a[0]; t[r][c4+1]=a[1]; t[r][c4+2]=a[2]; t[r][c4+3]=a[3];
  }
  __syncthreads();
  #pragma unroll
  for (int i = 0; i < 4; i++){
    int s = tid + 256*i;
    int nn = s >> 4, k4 = (s & 15)*4;
    f16x4 h;
    h[0]=(f16)t[k4][nn]; h[1]=(f16)t[k4+1][nn]; h[2]=(f16)t[k4+2][nn]; h[3]=(f16)t[k4+3][nn];
    *(f16x4*)&oT[((size_t)e*C_ + n0 + nn)*H_ + k0 + k4] = h;
  }
}

// ------------------------------------------------------------------
// gating v4: 8 tokens/block, 1024 blocks, no LDS staging (sim is L2-
// resident, 8-lane groups broadcast-read it). Wave = expert quad,
// lane = (tok l&7, k-eighth l>>3 -> 256-k stripe). f64 accumulation,
// shuffle reduce (8/16/32), 8-lane-parallel epilogue.
// ------------------------------------------------------------------
__global__ __launch_bounds__(256) void gate_kernel(const float* __restrict__ x,
    const float* __restrict__ sim, const double* __restrict__ wninv,
    const double* __restrict__ sigg, int* __restrict__ cnt,
    int* __restrict__ list, float* __restrict__ listw){
  __shared__ double dred[8][17];
  int tid = threadIdx.x;
  int wv = tid >> 6, l = tid & 63;
  int tok = l & 7, ko = l >> 3;       // ko in 0..7
  int n0 = blockIdx.x * 8;
  const float* xr = x + (size_t)(n0 + tok) * C_;
  const float* sp = sim + wv*4;       // expert quad base
  double accA[4] = {0,0,0,0}, accB[4] = {0,0,0,0};
  double ssqA = 0.0, ssqB = 0.0;
  int kbase = ko * 256;
  #pragma unroll 4
  for (int k = kbase; k < kbase + 256; k += 4){
    f32x4 xv = *(const f32x4*)&xr[k];
    #pragma unroll
    for (int j = 0; j < 4; j++){
      f32x4 sv = *(const f32x4*)&sp[(size_t)(k+j)*E_];
      double xd = (double)xv[j];
      if (j & 1){
        accB[0] += xd*(double)sv[0]; accB[1] += xd*(double)sv[1];
        accB[2] += xd*(double)sv[2]; accB[3] += xd*(double)sv[3];
        if (wv == 0) ssqB += xd*xd;
      } else {
        accA[0] += xd*(double)sv[0]; accA[1] += xd*(double)sv[1];
        accA[2] += xd*(double)sv[2]; accA[3] += xd*(double)sv[3];
        if (wv == 0) ssqA += xd*xd;
      }
    }
  }
  double acc[4];
  #pragma unroll
  for (int j = 0; j < 4; j++){
    acc[j] = accA[j] + accB[j];
    acc[j] += __shfl_xor(acc[j], 8);
    acc[j] += __shfl_xor(acc[j], 16);
    acc[j] += __shfl_xor(acc[j], 32);
  }
  double ssq = ssqA + ssqB;
  ssq += __shfl_xor(ssq, 8);
  ssq += __shfl_xor(ssq, 16);
  ssq += __shfl_xor(ssq, 32);
  if (l < 8){
    #pragma unroll
    for (int j = 0; j < 4; j++) dred[tok][wv*4 + j] = acc[j];
    if (wv == 0) dred[tok][16] = ssq;
  }
  __syncthreads();
  if (tid < 8){
    int n = n0 + tid;
    double inv = 1.0 / fmax(sqrt(dred[tid][16]), 1e-12);
    double logit[E_]; bool mask[E_]; int active = 0;
    #pragma unroll
    for (int e = 0; e < E_; e++){
      logit[e] = dred[tid][e] * inv * wninv[e] - sigg[e];
      mask[e] = logit[e] > 0.0;
      if (mask[e]) active++;
    }
    if (active == 0){
      int i1 = -1, i2 = -1; double b1 = -1e300, b2 = -1e300;
      for (int e = 0; e < E_; e++){
        double v = logit[e];
        if (v > b1){ b2 = b1; i2 = i1; b1 = v; i1 = e; }
        else if (v > b2){ b2 = v; i2 = e; }
      }
      mask[i1] = true; mask[i2] = true;
    }
    double mx = -1e300;
    for (int e = 0; e < E_; e++){ if (mask[e]) mx = fmax(mx, fmax(logit[e], 0.0)); }
    double ex[E_]; double sum = 0.0;
    for (int e = 0; e < E_; e++){
      double gval = fmax(logit[e], 0.0);
      ex[e] = mask[e] ? exp(gval - mx) : 0.0;
      sum += ex[e];
    }
    double isum = 1.0 / sum;
    for (int e = 0; e < E_; e++){
      if (mask[e]){
        int p = atomicAdd(&cnt[e], 1);
        list[e*N_TOK + p]  = n;
        listw[e*N_TOK + p] = (float)(ex[e]*isum);
      }
    }
  }
}

// ------------------------------------------------------------------
// tile lists: 64-gran (o_gemm) and 128-gran (qkv_gemm)
// ------------------------------------------------------------------
__global__ __launch_bounds__(64) void tile_builder(const int* __restrict__ cnt,
    int* __restrict__ tlist, int* __restrict__ ntile,
    int* __restrict__ tlist2, int* __restrict__ ntile2){
  __shared__ int nts[E_], nts2[E_];
  int tid = threadIdx.x;
  if (tid < E_){
    nts[tid]  = (cnt[tid] + 63) >> 6;
    nts2[tid] = (cnt[tid] + 127) >> 7;
  }
  __syncthreads();
  if (tid < E_){
    int base = 0, b2 = 0;
    for (int e = 0; e < tid; e++){ base += nts[e]; b2 += nts2[e]; }
    for (int t = 0; t < nts[tid];  t++) tlist[base + t] = (tid << 8) | t;
    for (int t = 0; t < nts2[tid]; t++) tlist2[b2 + t]  = (tid << 8) | t;
    if (tid == E_-1){ *ntile = base + nts[tid]; *ntile2 = b2 + nts2[tid]; }
  }
}

// ------------------------------------------------------------------
// grouped QKV GEMM v3 (m97 structure, unchanged)
// ------------------------------------------------------------------
__global__ __launch_bounds__(256, 2) void qkv_gemm(const f16* __restrict__ xh,
    const f16* __restrict__ wT, const int* __restrict__ cnt,
    const int* __restrict__ list, const float* __restrict__ listw,
    const int* __restrict__ tlist2, const int* __restrict__ ntile2,
    float* __restrict__ qkv){
  __shared__ __align__(16) f16 a_s[2][128][64];
  __shared__ __align__(16) f16 b_s[2][128][64];
  __shared__ int tok_s[128];
  __shared__ float wgt_s[128];
  int nitems = (*ntile2) * 3;
  int tid = threadIdx.x;
  int l = tid & 63, wv = tid >> 6;
  int wm = wv >> 1, wn = wv & 1;
  int g = l >> 4, c = l & 15;
  for (int w = blockIdx.x; w < nitems; w += gridDim.x){
    int tile = w / 3, nb = w - tile*3;
    int ent = tlist2[tile];
    int e = ent >> 8, mt = ent & 255;
    int ce = cnt[e];
    int m0 = mt * 128;
    if (tid < 128){
      int gr = m0 + tid;
      tok_s[tid] = (gr < ce) ? list[e*N_TOK + gr] : 0;
      wgt_s[tid] = (gr < ce) ? listw[e*N_TOK + gr] : 0.f;
    }
    __syncthreads();
    const f16* Bbase = wT + ((size_t)e*384 + nb*128)*C_;
    const f16* agp[4]; const f16* bgp[4];
    #pragma unroll
    for (int i = 0; i < 4; i++){
      int id = tid + 256*i;
      int row = id >> 3, ch = id & 7;
      agp[i] = xh + (size_t)tok_s[row]*C_ + ch*8;
      bgp[i] = Bbase + (size_t)row*C_ + ch*8;
    }
    f32x4 acc[4][4];
    #pragma unroll
    for (int m = 0; m < 4; m++)
      #pragma unroll
      for (int n = 0; n < 4; n++) acc[m][n] = (f32x4){0.f,0.f,0.f,0.f};
    #pragma unroll
    for (int i = 0; i < 4; i++){
      int id = tid + 256*i;
      gload16(agp[i], &a_s[0][0][0] + (size_t)id*8);
      gload16(bgp[i], &b_s[0][0][0] + (size_t)id*8);
    }
    __syncthreads();
    int cur = 0;
    for (int k0 = 0; k0 < C_; k0 += 64){
      int nxt = k0 + 64;
      if (nxt < C_){
        int nb2 = cur ^ 1;
        #pragma unroll
        for (int i = 0; i < 4; i++){
          int id = tid + 256*i;
          gload16(agp[i] + nxt, &a_s[nb2][0][0] + (size_t)id*8);
          gload16(bgp[i] + nxt, &b_s[nb2][0][0] + (size_t)id*8);
        }
      }
      #pragma unroll
      for (int ks = 0; ks < 2; ks++){
        f16x8 af[4], bf[4];
        #pragma unroll
        for (int m = 0; m < 4; m++)
          af[m] = *(const f16x8*)&a_s[cur][wm*64 + m*16 + c][ks*32 + 8*g];
        #pragma unroll
        for (int n = 0; n < 4; n++)
          bf[n] = *(const f16x8*)&b_s[cur][wn*64 + n*16 + c][ks*32 + 8*g];
        #pragma unroll
        for (int m = 0; m < 4; m++)
          #pragma unroll
          for (int n = 0; n < 4; n++)
            acc[m][n] = MFMA(af[m], bf[n], acc[m][n]);
      }
      __syncthreads();
      cur ^= 1;
    }
    #pragma unroll
    for (int m = 0; m < 4; m++){
      #pragma unroll
      for (int i = 0; i < 4; i++){
        int row = wm*64 + m*16 + 4*g + i;
        int gr = m0 + row;
        if (gr < ce){
          int tok = tok_s[row]; float wgt = wgt_s[row];
          #pragma unroll
          for (int n = 0; n < 4; n++){
            int col = nb*128 + wn*64 + n*16 + c;
            atomicAdd(&qkv[(size_t)tok*384 + col], wgt*acc[m][n][i]);
          }
        }
      }
    }
    __syncthreads();
  }
}

// ------------------------------------------------------------------
// RoPE on q,k halves of qkv buffer; emit fp16 q/k/v arrays
// ------------------------------------------------------------------
__global__ __launch_bounds__(192) void rope_kernel(const float* __restrict__ qkv,
    const int* __restrict__ pos_ids, f16* __restrict__ qh, f16* __restrict__ kh,
    f16* __restrict__ vh){
  int n = blockIdx.x; int tid = threadIdx.x;
  const float* row = qkv + (size_t)n * 384;
  if (tid < 128){
    int isK = tid >> 6, j = tid & 63;
    const float* src = row + isK*H_;
    float a = src[j], b = src[j+64];
    int pos = pos_ids[n & (T_-1)];
    float freq = exp2f(-(float)j * 0.20762050593046015f);
    float ang = (float)pos * freq;
    float s, cc;
    sincosf(ang, &s, &cc);
    f16* dst = isK ? kh : qh;
    dst[(size_t)n*H_ + j]      = (f16)(a*cc - b*s);
    dst[(size_t)n*H_ + j + 64] = (f16)(b*cc + a*s);
  } else {
    int j = (tid - 128)*2;
    vh[(size_t)n*H_ + j]     = (f16)row[256 + j];
    vh[(size_t)n*H_ + j + 1] = (f16)row[256 + j + 1];
  }
}

// ------------------------------------------------------------------
// flash attention, causal, D=128, k-split over NS_ striped segments.
// Inner tile math identical to the verified round-5 kernel; writes
// unnormalized partial (O, m, l) in f32 for the merge kernel.
// ------------------------------------------------------------------
#define LDK_ 136
#define LDV_ 72
__global__ __launch_bounds__(128) void attn_kernel(const f16* __restrict__ qh,
    const f16* __restrict__ kh, const f16* __restrict__ vh,
    float* __restrict__ Opart, float* __restrict__ mlpart){
  int bid = blockIdx.x;
  int seg = blockIdx.y;
  int b = bid >> 6, qt = bid & 63;
  int q0 = qt*32, nbase = b*T_;
  __shared__ __align__(16) f16 q_s[32*LDK_];
  __shared__ __align__(16) f16 k_s[64*LDK_];
  __shared__ __align__(16) f16 v_s[128*LDV_];
  __shared__ __align__(16) f16 p_s[2*16*LDV_];
  int tid = threadIdx.x;
  int l = tid & 63, w = tid >> 6;
  int g = l >> 4, c = l & 15;
  #pragma unroll
  for (int i = 0; i < 4; i++){
    int slot = tid + 128*i;
    int ch = slot & 15, r = slot >> 4;
    *(u32x4*)&q_s[r*LDK_ + ch*8] = *(const u32x4*)&qh[((size_t)(nbase + q0 + r))*H_ + ch*8];
  }
  f32x4 oacc[8];
  #pragma unroll
  for (int nb = 0; nb < 8; nb++) oacc[nb] = (f32x4){0,0,0,0};
  float m_run[4], l_run[4];
  #pragma unroll
  for (int i = 0; i < 4; i++){ m_run[i] = -1e30f; l_run[i] = 0.f; }
  int nk = (q0 + 31)/64 + 1;
  for (int kt = seg; kt < nk; kt += NS_){
    int kb = kt*64;
    __syncthreads();
    #pragma unroll
    for (int i = 0; i < 8; i++){
      int slot = tid + 128*i;
      int ch = slot & 15, r = slot >> 4;
      *(u32x4*)&k_s[r*LDK_ + ch*8] = *(const u32x4*)&kh[((size_t)(nbase + kb + r))*H_ + ch*8];
    }
    #pragma unroll
    for (int i = 0; i < 8; i++){
      int slot = tid + 128*i;
      int tok = slot & 63, ch = slot >> 6;
      f16x8 raw = *(const f16x8*)&vh[((size_t)(nbase + kb + tok))*H_ + ch*8];
      #pragma unroll
      for (int j = 0; j < 8; j++) v_s[(ch*8 + j)*LDV_ + tok] = raw[j];
    }
    __syncthreads();
    f32x4 sacc[4];
    #pragma unroll
    for (int f = 0; f < 4; f++) sacc[f] = (f32x4){0,0,0,0};
    #pragma unroll
    for (int ks = 0; ks < 4; ks++){
      f16x8 qf = *(const f16x8*)&q_s[(w*16 + c)*LDK_ + ks*32 + 8*g];
      #pragma unroll
      for (int f = 0; f < 4; f++){
        f16x8 kf = *(const f16x8*)&k_s[(f*16 + c)*LDK_ + ks*32 + 8*g];
        sacc[f] = MFMA(qf, kf, sacc[f]);
      }
    }
    float tm[4];
    #pragma unroll
    for (int i = 0; i < 4; i++) tm[i] = -1e30f;
    #pragma unroll
    for (int f = 0; f < 4; f++){
      int kg = kb + f*16 + c;
      #pragma unroll
      for (int i = 0; i < 4; i++){
        int qg = q0 + w*16 + 4*g + i;
        float s = sacc[f][i] * SCALE_;
        if (kg > qg) s = -1e30f;
        sacc[f][i] = s;
        tm[i] = fmaxf(tm[i], s);
      }
    }
    #pragma unroll
    for (int i = 0; i < 4; i++){
      #pragma unroll
      for (int d = 1; d <= 8; d <<= 1) tm[i] = fmaxf(tm[i], __shfl_xor(tm[i], d));
      float mn = fmaxf(m_run[i], tm[i]);
      float al = __expf(m_run[i] - mn);
      m_run[i] = mn;
      l_run[i] *= al;
      #pragma unroll
      for (int nb = 0; nb < 8; nb++) oacc[nb][i] *= al;
    }
    float rs[4] = {0.f,0.f,0.f,0.f};
    #pragma unroll
    for (int f = 0; f < 4; f++){
      #pragma unroll
      for (int i = 0; i < 4; i++){
        float p = __expf(sacc[f][i] - m_run[i]);
        rs[i] += p;
        p_s[w*16*LDV_ + (4*g + i)*LDV_ + f*16 + c] = (f16)p;
      }
    }
    #pragma unroll
    for (int i = 0; i < 4; i++){
      #pragma unroll
      for (int d = 1; d <= 8; d <<= 1) rs[i] += __shfl_xor(rs[i], d);
      l_run[i] += rs[i];
    }
    #pragma unroll
    for (int ks = 0; ks < 2; ks++){
      f16x8 pf = *(const f16x8*)&p_s[w*16*LDV_ + c*LDV_ + ks*32 + 8*g];
      #pragma unroll
      for (int nb = 0; nb < 8; nb++){
        f16x8 vf = *(const f16x8*)&v_s[(c + 16*nb)*LDV_ + ks*32 + 8*g];
        oacc[nb] = MFMA(pf, vf, oacc[nb]);
      }
    }
  }
  #pragma unroll
  for (int i = 0; i < 4; i++){
    int row = w*16 + 4*g + i;
    size_t base = ((size_t)(seg*256 + bid)*32 + row);
    if (c == 0){
      mlpart[base*2]     = m_run[i];
      mlpart[base*2 + 1] = l_run[i];
    }
    float* orow = Opart + base*128;
    #pragma unroll
    for (int nb = 0; nb < 8; nb++)
      orow[c + 16*nb] = oacc[nb][i];
  }
}

// ------------------------------------------------------------------
// merge k-split partials: O = sum_s e^{m_s-m} O_s / sum_s e^{m_s-m} l_s
// ------------------------------------------------------------------
__global__ __launch_bounds__(128) void attn_merge(const float* __restrict__ Opart,
    const float* __restrict__ mlpart, f16* __restrict__ ah){
  int bid = blockIdx.x;
  int tid = threadIdx.x;
  int row = tid & 31, d0 = (tid >> 5) * 32;
  float ms[NS_], lv[NS_], wgt[NS_];
  float m = -3e38f;
  #pragma unroll
  for (int s = 0; s < NS_; s++){
    size_t base = ((size_t)(s*256 + bid)*32 + row);
    ms[s] = mlpart[base*2];
    lv[s] = mlpart[base*2 + 1];
    m = fmaxf(m, ms[s]);
  }
  float wsum = 0.f;
  #pragma unroll
  for (int s = 0; s < NS_; s++){ wgt[s] = __expf(ms[s] - m); wsum += wgt[s]*lv[s]; }
  float inv = 1.f / wsum;
  int token = (bid >> 6)*T_ + (bid & 63)*32 + row;
  #pragma unroll
  for (int dd = 0; dd < 32; dd += 4){
    f32x4 o = (f32x4){0,0,0,0};
    #pragma unroll
    for (int s = 0; s < NS_; s++){
      f32x4 p = *(const f32x4*)&Opart[(((size_t)(s*256 + bid)*32 + row))*128 + d0 + dd];
      o[0] += wgt[s]*p[0]; o[1] += wgt[s]*p[1]; o[2] += wgt[s]*p[2]; o[3] += wgt[s]*p[3];
    }
    f16x4 h;
    h[0]=(f16)(o[0]*inv); h[1]=(f16)(o[1]*inv); h[2]=(f16)(o[2]*inv); h[3]=(f16)(o[3]*inv);
    *(f16x4*)&ah[(size_t)token*H_ + d0 + dd] = h;
  }
}

// ------------------------------------------------------------------
// grouped O GEMM v2 (unchanged): tile-list driven, K=128 single stage
// ------------------------------------------------------------------
#define LDT 136
__global__ __launch_bounds__(256) void o_gemm(const f16* __restrict__ ah,
    const f16* __restrict__ oT, const int* __restrict__ cnt,
    const int* __restrict__ list, const float* __restrict__ listw,
    const int* __restrict__ tlist, const int* __restrict__ ntile,
    float* __restrict__ out){
  __shared__ __align__(16) f16 a_s[64*LDT];
  __shared__ __align__(16) f16 b_s[128*LDT];
  __shared__ int tok_s[64];
  __shared__ float wgt_s[64];
  int nitems = (*ntile) * 16;
  int tid = threadIdx.x;
  int l = tid & 63, wv = tid >> 6;
  int wm = wv >> 1, wn = wv & 1;
  int g = l >> 4, c = l & 15;
  for (int w = blockIdx.x; w < nitems; w += gridDim.x){
    int tile = w >> 4, nbt = w & 15;
    int ent = tlist[tile];
    int e = ent >> 8, mt = ent & 255;
    int ce = cnt[e];
    int m0 = mt * 64, n0 = nbt * 128;
    if (tid < 64){
      int gr = m0 + tid;
      tok_s[tid] = (gr < ce) ? list[e*N_TOK + gr] : 0;
      wgt_s[tid] = (gr < ce) ? listw[e*N_TOK + gr] : 0.f;
    }
    __syncthreads();
    #pragma unroll
    for (int i = 0; i < 4; i++){
      int s = tid + 256*i;
      int r = s >> 4, cs = (s & 15)*8;
      f16x8 v = *(const f16x8*)&ah[(size_t)tok_s[r]*H_ + cs];
      float wgt = wgt_s[r];
      f16x8 o;
      #pragma unroll
      for (int j = 0; j < 8; j++) o[j] = (f16)((float)v[j]*wgt);
      *(f16x8*)&a_s[r*LDT + cs] = o;
    }
    #pragma unroll
    for (int i = 0; i < 8; i++){
      int s = tid + 256*i;
      int j = s >> 4, cs = (s & 15)*8;
      f16x8 v = *(const f16x8*)&oT[((size_t)e*C_ + n0 + j)*H_ + cs];
      *(f16x8*)&b_s[j*LDT + cs] = v;
    }
    __syncthreads();
    f32x4 acc[2][4];
    #pragma unroll
    for (int m = 0; m < 2; m++)
      #pragma unroll
      for (int n = 0; n < 4; n++) acc[m][n] = (f32x4){0.f,0.f,0.f,0.f};
    #pragma unroll
    for (int ks = 0; ks < 4; ks++){
      f16x8 af[2], bf[4];
      #pragma unroll
      for (int m = 0; m < 2; m++)
        af[m] = *(const f16x8*)&a_s[(wm*32 + m*16 + c)*LDT + ks*32 + 8*g];
      #pragma unroll
      for (int n = 0; n < 4; n++)
        bf[n] = *(const f16x8*)&b_s[(wn*64 + n*16 + c)*LDT + ks*32 + 8*g];
      #pragma unroll
      for (int m = 0; m < 2; m++)
        #pragma unroll
        for (int n = 0; n < 4; n++)
          acc[m][n] = MFMA(af[m], bf[n], acc[m][n]);
    }
    #pragma unroll
    for (int m = 0; m < 2; m++){
      #pragma unroll
      for (int i = 0; i < 4; i++){
        int row = wm*32 + m*16 + 4*g + i;
        int gr = m0 + row;
        if (gr < ce){
          int tok = tok_s[row];
          #pragma unroll
          for (int n = 0; n < 4; n++){
            int col = n0 + wn*64 + n*16 + c;
            atomicAdd(&out[(size_t)tok*C_ + col], acc[m][n][i]);
          }
        }
      }
    }
    __syncthreads();
  }
}

// ------------------------------------------------------------------
extern "C" void kernel_launch(void* const* d_in, const int* in_sizes, int n_in,
                              void* d_out, int out_size, void* d_ws, size_t ws_size,
                              hipStream_t stream){
  const float* hs    = (const float*)d_in[0];
  const int*   pos   = (const int*)d_in[1];
  const float* sim   = (const float*)d_in[2];
  const float* gates = (const float*)d_in[3];
  const float* qp    = (const float*)d_in[4];
  const float* kp    = (const float*)d_in[5];
  const float* vp    = (const float*)d_in[6];
  const float* op    = (const float*)d_in[7];
  float* out = (float*)d_out;
  char* ws = (char*)d_ws;
  // workspace layout (same extent as round 4/5: ends 89137664)
  int*    cnt    = (int*)(ws + 0);               // 16 int
  int*    ntile  = (int*)(ws + 64);              // 1 int
  double* wninv  = (double*)(ws + 128);          // 16 f64
  double* sigg   = (double*)(ws + 256);          // 16 f64
  int*    tlist  = (int*)(ws + 512);             // 2048 int (64-gran)
  int*    list   = (int*)(ws + 8704);            // 16*8192 int
  float*  listw  = (float*)(ws + 532992);        // 16*8192 f32
  f16*    xh     = (f16*)(ws + 1057280);         // [8192][2048] (dead after qkv_gemm)
  float*  Opart  = (float*)(ws + 1057280);       // overlays xh: [4][256][32][128] f32
  float*  mlpart = (float*)(ws + 17834496);      // overlays xh: [4][256][32][2] f32
  f16*    wT     = (f16*)(ws + 34611712);        // [16][384][2048]
  f16*    oT     = (f16*)(ws + 59777536);        // [16][2048][128]
  float*  qkv    = (float*)(ws + 68166144);      // [8192][384] f32
  f16*    ah     = (f16*)(ws + 68166144);        // overlays qkv (dead after rope)
  f16*    qh     = (f16*)(ws + 80749056);        // [8192][128]
  f16*    kh     = (f16*)(ws + 82846208);
  f16*    vh     = (f16*)(ws + 84943360);
  int*    tlist2 = (int*)(ws + 87040512);        // 1024 int (128-gran)
  int*    ntile2 = (int*)(ws + 87044608);        // 1 int

  hipMemsetAsync(cnt, 0, 64, stream);
  hipMemsetAsync(qkv, 0, (size_t)N_TOK*384*4, stream);
  hipMemsetAsync(out, 0, (size_t)N_TOK*C_*4, stream);

  prep_kernel<<<1, 256, 0, stream>>>(sim, gates, wninv, sigg);
  conv_x<<<4096, 256, 0, stream>>>(hs, xh);
  conv_w<<<dim3(32, 2, 48), 256, 0, stream>>>(qp, kp, vp, wT);
  conv_o<<<dim3(32, 2, 16), 256, 0, stream>>>(op, oT);
  gate_kernel<<<1024, 256, 0, stream>>>(hs, sim, wninv, sigg, cnt, list, listw);
  tile_builder<<<1, 64, 0, stream>>>(cnt, tlist, ntile, tlist2, ntile2);
  qkv_gemm<<<512, 256, 0, stream>>>(xh, wT, cnt, list, listw, tlist2, ntile2, qkv);
  rope_kernel<<<N_TOK, 192, 0, stream>>>(qkv, pos, qh, kh, vh);
  attn_kernel<<<dim3(256, NS_), 128, 0, stream>>>(qh, kh, vh, Opart, mlpart);
  attn_merge<<<256, 128, 0, stream>>>(Opart, mlpart, ah);
  o_gemm<<<2048, 256, 0, stream>>>(ah, oT, cnt, list, listw, tlist, ntile, out);
}

// Round 7
// 548.935 us; speedup vs baseline: 1.2283x; 1.2283x over previous
//
#include <hip/hip_runtime.h>
#include <hip/hip_fp16.h>

#define T_ 2048
#define C_ 2048
#define H_ 128
#define E_ 16
#define N_TOK 8192
#define NS_ 4
#define SCALE_ 0.08838834764831845f   // 1/sqrt(128)

typedef _Float16 f16;
typedef _Float16 f16x4 __attribute__((ext_vector_type(4)));
typedef _Float16 f16x8 __attribute__((ext_vector_type(8)));
typedef float f32x4 __attribute__((ext_vector_type(4)));
typedef unsigned int u32x4 __attribute__((ext_vector_type(4)));

#define MFMA(a,b,c) __builtin_amdgcn_mfma_f32_16x16x32_f16(a,b,c,0,0,0)

__device__ __forceinline__ void gload16(const void* g, void* l){
  __builtin_amdgcn_global_load_lds(
      (const __attribute__((address_space(1))) unsigned int*)g,
      (__attribute__((address_space(3))) unsigned int*)l, 16, 0, 0);
}

// ------------------------------------------------------------------
// prep: column norms of sim_matrix (inverse, f64), sigmoid(gates)
// ------------------------------------------------------------------
__global__ __launch_bounds__(256) void prep_kernel(const float* __restrict__ sim,
    const float* __restrict__ gates, double* __restrict__ wninv, double* __restrict__ sigg){
  __shared__ double part[16][17];
  int tid = threadIdx.x;
  int col = tid & 15, grp = tid >> 4;
  double ssq = 0.0;
  for (int r = grp; r < C_; r += 16){ float v = sim[r*E_ + col]; ssq += (double)v*(double)v; }
  part[grp][col] = ssq;
  __syncthreads();
  if (tid < E_){
    double s = 0.0;
    #pragma unroll
    for (int g2 = 0; g2 < 16; g2++) s += part[g2][tid];
    wninv[tid] = 1.0 / fmax(sqrt(s), 1e-12);
    sigg[tid]  = 1.0 / (1.0 + exp(-(double)gates[tid]));
  }
}

// ------------------------------------------------------------------
// converts: x -> f16; q/k/v_proj -> f16 transposed [e][384][2048];
// o_proj -> f16 transposed [e][2048][128]
// ------------------------------------------------------------------
__global__ __launch_bounds__(256) void conv_x(const float* __restrict__ x, f16* __restrict__ xh){
  for (int v = blockIdx.x*256 + threadIdx.x; v < N_TOK*C_/4; v += 4096*256){
    f32x4 a = *(const f32x4*)&x[(size_t)v*4];
    f16x4 h; h[0]=(f16)a[0]; h[1]=(f16)a[1]; h[2]=(f16)a[2]; h[3]=(f16)a[3];
    *(f16x4*)&xh[(size_t)v*4] = h;
  }
}

__global__ __launch_bounds__(256) void conv_w(const float* __restrict__ qp,
    const float* __restrict__ kp, const float* __restrict__ vp, f16* __restrict__ wT){
  int ep = blockIdx.z; int e = ep/3, proj = ep - 3*e;
  const float* W = (proj==0?qp:(proj==1?kp:vp)) + (size_t)e*C_*H_;
  int k0 = blockIdx.x*64, j0 = blockIdx.y*64;
  __shared__ float t[64][65];
  int tid = threadIdx.x;
  #pragma unroll
  for (int i = 0; i < 4; i++){
    int s = tid + 256*i;
    int r = s >> 4, c4 = (s & 15)*4;
    f32x4 a = *(const f32x4*)&W[(size_t)(k0+r)*H_ + j0 + c4];
    t[r][c4]=a[0]; t[r][c4+1]=a[1]; t[r][c4+2]=a[2]; t[r][c4+3]=a[3];
  }
  __syncthreads();
  #pragma unroll
  for (int i = 0; i < 4; i++){
    int s = tid + 256*i;
    int jj = s >> 4, k4 = (s & 15)*4;
    f16x4 h;
    h[0]=(f16)t[k4][jj]; h[1]=(f16)t[k4+1][jj]; h[2]=(f16)t[k4+2][jj]; h[3]=(f16)t[k4+3][jj];
    *(f16x4*)&wT[((size_t)e*384 + proj*128 + j0 + jj)*C_ + k0 + k4] = h;
  }
}

__global__ __launch_bounds__(256) void conv_o(const float* __restrict__ op, f16* __restrict__ oT){
  int e = blockIdx.z;
  int n0 = blockIdx.x*64, k0 = blockIdx.y*64;
  __shared__ float t[64][65];
  int tid = threadIdx.x;
  #pragma unroll
  for (int i = 0; i < 4; i++){
    int s = tid + 256*i;
    int r = s >> 4, c4 = (s & 15)*4;   // r: k, c4: n
    f32x4 a = *(const f32x4*)&op[(size_t)e*H_*C_ + (size_t)(k0+r)*C_ + n0 + c4];
    t[r][c4]=a[0]; t[r][c4+1]=a[1]; t[r][c4+2]=a[2]; t[r][c4+3]=a[3];
  }
  __syncthreads();
  #pragma unroll
  for (int i = 0; i < 4; i++){
    int s = tid + 256*i;
    int nn = s >> 4, k4 = (s & 15)*4;
    f16x4 h;
    h[0]=(f16)t[k4][nn]; h[1]=(f16)t[k4+1][nn]; h[2]=(f16)t[k4+2][nn]; h[3]=(f16)t[k4+3][nn];
    *(f16x4*)&oT[((size_t)e*C_ + n0 + nn)*H_ + k0 + k4] = h;
  }
}

// ------------------------------------------------------------------
// gating v5 = v3 structure + split-k(4), deterministic partials.
// gate_dot: 32 toks/block, 512-k slice, LDS-staged sim, f64 accum.
// ------------------------------------------------------------------
__global__ __launch_bounds__(256) void gate_dot(const float* __restrict__ x,
    const float* __restrict__ sim, double* __restrict__ dpart){
  __shared__ __align__(16) float st[4096];   // sim chunk [256 k][16 e]
  int tid = threadIdx.x;
  int eq = tid >> 6, l = tid & 63;
  int tok = l & 31, kh = l >> 5;
  int n0 = blockIdx.x * 32;
  int seg = blockIdx.y;
  const float* xr = x + (size_t)(n0 + tok) * C_;
  double accA[4] = {0,0,0,0}, accB[4] = {0,0,0,0};
  double ssqA = 0.0, ssqB = 0.0;
  for (int k0 = seg*512; k0 < seg*512 + 512; k0 += 256){
    __syncthreads();
    #pragma unroll
    for (int i = 0; i < 4; i++){
      int idx = tid + 256*i;
      *(f32x4*)&st[idx*4] = *(const f32x4*)&sim[(size_t)k0*E_ + idx*4];
    }
    __syncthreads();
    #pragma unroll
    for (int q = 0; q < 32; q++){
      int kl = kh*128 + q*4;
      f32x4 xv = *(const f32x4*)&xr[k0 + kl];
      #pragma unroll
      for (int j = 0; j < 4; j++){
        f32x4 sv = *(const f32x4*)&st[(kl+j)*E_ + eq*4];
        double xd = (double)xv[j];
        if (j & 1){
          accB[0] += xd*(double)sv[0]; accB[1] += xd*(double)sv[1];
          accB[2] += xd*(double)sv[2]; accB[3] += xd*(double)sv[3];
          if (eq == 0) ssqB += xd*xd;
        } else {
          accA[0] += xd*(double)sv[0]; accA[1] += xd*(double)sv[1];
          accA[2] += xd*(double)sv[2]; accA[3] += xd*(double)sv[3];
          if (eq == 0) ssqA += xd*xd;
        }
      }
    }
  }
  double acc[4];
  #pragma unroll
  for (int j = 0; j < 4; j++){
    acc[j] = accA[j] + accB[j];
    acc[j] += __shfl_xor(acc[j], 32);
  }
  double ssq = ssqA + ssqB;
  ssq += __shfl_xor(ssq, 32);
  if (l < 32){
    double* dst = dpart + ((size_t)seg*N_TOK + n0 + tok)*17;
    #pragma unroll
    for (int j = 0; j < 4; j++) dst[eq*4 + j] = acc[j];
    if (eq == 0) dst[16] = ssq;
  }
}

// ------------------------------------------------------------------
// gate_route: per-token f64 epilogue (sum segs in fixed order,
// logits -> mask -> top2 fallback -> masked softmax -> lists)
// ------------------------------------------------------------------
__global__ __launch_bounds__(256) void gate_route(const double* __restrict__ dpart,
    const double* __restrict__ wninv, const double* __restrict__ sigg,
    int* __restrict__ cnt, int* __restrict__ list, float* __restrict__ listw){
  int n = blockIdx.x*256 + threadIdx.x;
  double v[17];
  #pragma unroll
  for (int j = 0; j < 17; j++) v[j] = 0.0;
  for (int s = 0; s < NS_; s++){
    const double* p = dpart + ((size_t)s*N_TOK + n)*17;
    #pragma unroll
    for (int j = 0; j < 17; j++) v[j] += p[j];
  }
  double inv = 1.0 / fmax(sqrt(v[16]), 1e-12);
  double logit[E_]; bool mask[E_]; int active = 0;
  #pragma unroll
  for (int e = 0; e < E_; e++){
    logit[e] = v[e] * inv * wninv[e] - sigg[e];
    mask[e] = logit[e] > 0.0;
    if (mask[e]) active++;
  }
  if (active == 0){
    int i1 = -1, i2 = -1; double b1 = -1e300, b2 = -1e300;
    for (int e = 0; e < E_; e++){
      double vv = logit[e];
      if (vv > b1){ b2 = b1; i2 = i1; b1 = vv; i1 = e; }
      else if (vv > b2){ b2 = vv; i2 = e; }
    }
    mask[i1] = true; mask[i2] = true;
  }
  double mx = -1e300;
  for (int e = 0; e < E_; e++){ if (mask[e]) mx = fmax(mx, fmax(logit[e], 0.0)); }
  double ex[E_]; double sum = 0.0;
  for (int e = 0; e < E_; e++){
    double gval = fmax(logit[e], 0.0);
    ex[e] = mask[e] ? exp(gval - mx) : 0.0;
    sum += ex[e];
  }
  double isum = 1.0 / sum;
  for (int e = 0; e < E_; e++){
    if (mask[e]){
      int p = atomicAdd(&cnt[e], 1);
      list[e*N_TOK + p]  = n;
      listw[e*N_TOK + p] = (float)(ex[e]*isum);
    }
  }
}

// ------------------------------------------------------------------
// tile lists: 64-gran (o_gemm) and 128-gran (qkv_gemm)
// ------------------------------------------------------------------
__global__ __launch_bounds__(64) void tile_builder(const int* __restrict__ cnt,
    int* __restrict__ tlist, int* __restrict__ ntile,
    int* __restrict__ tlist2, int* __restrict__ ntile2){
  __shared__ int nts[E_], nts2[E_];
  int tid = threadIdx.x;
  if (tid < E_){
    nts[tid]  = (cnt[tid] + 63) >> 6;
    nts2[tid] = (cnt[tid] + 127) >> 7;
  }
  __syncthreads();
  if (tid < E_){
    int base = 0, b2 = 0;
    for (int e = 0; e < tid; e++){ base += nts[e]; b2 += nts2[e]; }
    for (int t = 0; t < nts[tid];  t++) tlist[base + t] = (tid << 8) | t;
    for (int t = 0; t < nts2[tid]; t++) tlist2[b2 + t]  = (tid << 8) | t;
    if (tid == E_-1){ *ntile = base + nts[tid]; *ntile2 = b2 + nts2[tid]; }
  }
}

// ------------------------------------------------------------------
// grouped QKV GEMM v3 (m97 structure, unchanged)
// ------------------------------------------------------------------
__global__ __launch_bounds__(256, 2) void qkv_gemm(const f16* __restrict__ xh,
    const f16* __restrict__ wT, const int* __restrict__ cnt,
    const int* __restrict__ list, const float* __restrict__ listw,
    const int* __restrict__ tlist2, const int* __restrict__ ntile2,
    float* __restrict__ qkv){
  __shared__ __align__(16) f16 a_s[2][128][64];
  __shared__ __align__(16) f16 b_s[2][128][64];
  __shared__ int tok_s[128];
  __shared__ float wgt_s[128];
  int nitems = (*ntile2) * 3;
  int tid = threadIdx.x;
  int l = tid & 63, wv = tid >> 6;
  int wm = wv >> 1, wn = wv & 1;
  int g = l >> 4, c = l & 15;
  for (int w = blockIdx.x; w < nitems; w += gridDim.x){
    int tile = w / 3, nb = w - tile*3;
    int ent = tlist2[tile];
    int e = ent >> 8, mt = ent & 255;
    int ce = cnt[e];
    int m0 = mt * 128;
    if (tid < 128){
      int gr = m0 + tid;
      tok_s[tid] = (gr < ce) ? list[e*N_TOK + gr] : 0;
      wgt_s[tid] = (gr < ce) ? listw[e*N_TOK + gr] : 0.f;
    }
    __syncthreads();
    const f16* Bbase = wT + ((size_t)e*384 + nb*128)*C_;
    const f16* agp[4]; const f16* bgp[4];
    #pragma unroll
    for (int i = 0; i < 4; i++){
      int id = tid + 256*i;
      int row = id >> 3, ch = id & 7;
      agp[i] = xh + (size_t)tok_s[row]*C_ + ch*8;
      bgp[i] = Bbase + (size_t)row*C_ + ch*8;
    }
    f32x4 acc[4][4];
    #pragma unroll
    for (int m = 0; m < 4; m++)
      #pragma unroll
      for (int n = 0; n < 4; n++) acc[m][n] = (f32x4){0.f,0.f,0.f,0.f};
    #pragma unroll
    for (int i = 0; i < 4; i++){
      int id = tid + 256*i;
      gload16(agp[i], &a_s[0][0][0] + (size_t)id*8);
      gload16(bgp[i], &b_s[0][0][0] + (size_t)id*8);
    }
    __syncthreads();
    int cur = 0;
    for (int k0 = 0; k0 < C_; k0 += 64){
      int nxt = k0 + 64;
      if (nxt < C_){
        int nb2 = cur ^ 1;
        #pragma unroll
        for (int i = 0; i < 4; i++){
          int id = tid + 256*i;
          gload16(agp[i] + nxt, &a_s[nb2][0][0] + (size_t)id*8);
          gload16(bgp[i] + nxt, &b_s[nb2][0][0] + (size_t)id*8);
        }
      }
      #pragma unroll
      for (int ks = 0; ks < 2; ks++){
        f16x8 af[4], bf[4];
        #pragma unroll
        for (int m = 0; m < 4; m++)
          af[m] = *(const f16x8*)&a_s[cur][wm*64 + m*16 + c][ks*32 + 8*g];
        #pragma unroll
        for (int n = 0; n < 4; n++)
          bf[n] = *(const f16x8*)&b_s[cur][wn*64 + n*16 + c][ks*32 + 8*g];
        #pragma unroll
        for (int m = 0; m < 4; m++)
          #pragma unroll
          for (int n = 0; n < 4; n++)
            acc[m][n] = MFMA(af[m], bf[n], acc[m][n]);
      }
      __syncthreads();
      cur ^= 1;
    }
    #pragma unroll
    for (int m = 0; m < 4; m++){
      #pragma unroll
      for (int i = 0; i < 4; i++){
        int row = wm*64 + m*16 + 4*g + i;
        int gr = m0 + row;
        if (gr < ce){
          int tok = tok_s[row]; float wgt = wgt_s[row];
          #pragma unroll
          for (int n = 0; n < 4; n++){
            int col = nb*128 + wn*64 + n*16 + c;
            atomicAdd(&qkv[(size_t)tok*384 + col], wgt*acc[m][n][i]);
          }
        }
      }
    }
    __syncthreads();
  }
}

// ------------------------------------------------------------------
// RoPE on q,k halves of qkv buffer; emit fp16 q/k/v arrays
// ------------------------------------------------------------------
__global__ __launch_bounds__(192) void rope_kernel(const float* __restrict__ qkv,
    const int* __restrict__ pos_ids, f16* __restrict__ qh, f16* __restrict__ kh,
    f16* __restrict__ vh){
  int n = blockIdx.x; int tid = threadIdx.x;
  const float* row = qkv + (size_t)n * 384;
  if (tid < 128){
    int isK = tid >> 6, j = tid & 63;
    const float* src = row + isK*H_;
    float a = src[j], b = src[j+64];
    int pos = pos_ids[n & (T_-1)];
    float freq = exp2f(-(float)j * 0.20762050593046015f);
    float ang = (float)pos * freq;
    float s, cc;
    sincosf(ang, &s, &cc);
    f16* dst = isK ? kh : qh;
    dst[(size_t)n*H_ + j]      = (f16)(a*cc - b*s);
    dst[(size_t)n*H_ + j + 64] = (f16)(b*cc + a*s);
  } else {
    int j = (tid - 128)*2;
    vh[(size_t)n*H_ + j]     = (f16)row[256 + j];
    vh[(size_t)n*H_ + j + 1] = (f16)row[256 + j + 1];
  }
}

// ------------------------------------------------------------------
// flash attention, causal, D=128, k-split over NS_ striped segments
// (unchanged from round 6)
// ------------------------------------------------------------------
#define LDK_ 136
#define LDV_ 72
__global__ __launch_bounds__(128) void attn_kernel(const f16* __restrict__ qh,
    const f16* __restrict__ kh, const f16* __restrict__ vh,
    float* __restrict__ Opart, float* __restrict__ mlpart){
  int bid = blockIdx.x;
  int seg = blockIdx.y;
  int b = bid >> 6, qt = bid & 63;
  int q0 = qt*32, nbase = b*T_;
  __shared__ __align__(16) f16 q_s[32*LDK_];
  __shared__ __align__(16) f16 k_s[64*LDK_];
  __shared__ __align__(16) f16 v_s[128*LDV_];
  __shared__ __align__(16) f16 p_s[2*16*LDV_];
  int tid = threadIdx.x;
  int l = tid & 63, w = tid >> 6;
  int g = l >> 4, c = l & 15;
  #pragma unroll
  for (int i = 0; i < 4; i++){
    int slot = tid + 128*i;
    int ch = slot & 15, r = slot >> 4;
    *(u32x4*)&q_s[r*LDK_ + ch*8] = *(const u32x4*)&qh[((size_t)(nbase + q0 + r))*H_ + ch*8];
  }
  f32x4 oacc[8];
  #pragma unroll
  for (int nb = 0; nb < 8; nb++) oacc[nb] = (f32x4){0,0,0,0};
  float m_run[4], l_run[4];
  #pragma unroll
  for (int i = 0; i < 4; i++){ m_run[i] = -1e30f; l_run[i] = 0.f; }
  int nk = (q0 + 31)/64 + 1;
  for (int kt = seg; kt < nk; kt += NS_){
    int kb = kt*64;
    __syncthreads();
    #pragma unroll
    for (int i = 0; i < 8; i++){
      int slot = tid + 128*i;
      int ch = slot & 15, r = slot >> 4;
      *(u32x4*)&k_s[r*LDK_ + ch*8] = *(const u32x4*)&kh[((size_t)(nbase + kb + r))*H_ + ch*8];
    }
    #pragma unroll
    for (int i = 0; i < 8; i++){
      int slot = tid + 128*i;
      int tok = slot & 63, ch = slot >> 6;
      f16x8 raw = *(const f16x8*)&vh[((size_t)(nbase + kb + tok))*H_ + ch*8];
      #pragma unroll
      for (int j = 0; j < 8; j++) v_s[(ch*8 + j)*LDV_ + tok] = raw[j];
    }
    __syncthreads();
    f32x4 sacc[4];
    #pragma unroll
    for (int f = 0; f < 4; f++) sacc[f] = (f32x4){0,0,0,0};
    #pragma unroll
    for (int ks = 0; ks < 4; ks++){
      f16x8 qf = *(const f16x8*)&q_s[(w*16 + c)*LDK_ + ks*32 + 8*g];
      #pragma unroll
      for (int f = 0; f < 4; f++){
        f16x8 kf = *(const f16x8*)&k_s[(f*16 + c)*LDK_ + ks*32 + 8*g];
        sacc[f] = MFMA(qf, kf, sacc[f]);
      }
    }
    float tm[4];
    #pragma unroll
    for (int i = 0; i < 4; i++) tm[i] = -1e30f;
    #pragma unroll
    for (int f = 0; f < 4; f++){
      int kg = kb + f*16 + c;
      #pragma unroll
      for (int i = 0; i < 4; i++){
        int qg = q0 + w*16 + 4*g + i;
        float s = sacc[f][i] * SCALE_;
        if (kg > qg) s = -1e30f;
        sacc[f][i] = s;
        tm[i] = fmaxf(tm[i], s);
      }
    }
    #pragma unroll
    for (int i = 0; i < 4; i++){
      #pragma unroll
      for (int d = 1; d <= 8; d <<= 1) tm[i] = fmaxf(tm[i], __shfl_xor(tm[i], d));
      float mn = fmaxf(m_run[i], tm[i]);
      float al = __expf(m_run[i] - mn);
      m_run[i] = mn;
      l_run[i] *= al;
      #pragma unroll
      for (int nb = 0; nb < 8; nb++) oacc[nb][i] *= al;
    }
    float rs[4] = {0.f,0.f,0.f,0.f};
    #pragma unroll
    for (int f = 0; f < 4; f++){
      #pragma unroll
      for (int i = 0; i < 4; i++){
        float p = __expf(sacc[f][i] - m_run[i]);
        rs[i] += p;
        p_s[w*16*LDV_ + (4*g + i)*LDV_ + f*16 + c] = (f16)p;
      }
    }
    #pragma unroll
    for (int i = 0; i < 4; i++){
      #pragma unroll
      for (int d = 1; d <= 8; d <<= 1) rs[i] += __shfl_xor(rs[i], d);
      l_run[i] += rs[i];
    }
    #pragma unroll
    for (int ks = 0; ks < 2; ks++){
      f16x8 pf = *(const f16x8*)&p_s[w*16*LDV_ + c*LDV_ + ks*32 + 8*g];
      #pragma unroll
      for (int nb = 0; nb < 8; nb++){
        f16x8 vf = *(const f16x8*)&v_s[(c + 16*nb)*LDV_ + ks*32 + 8*g];
        oacc[nb] = MFMA(pf, vf, oacc[nb]);
      }
    }
  }
  #pragma unroll
  for (int i = 0; i < 4; i++){
    int row = w*16 + 4*g + i;
    size_t base = ((size_t)(seg*256 + bid)*32 + row);
    if (c == 0){
      mlpart[base*2]     = m_run[i];
      mlpart[base*2 + 1] = l_run[i];
    }
    float* orow = Opart + base*128;
    #pragma unroll
    for (int nb = 0; nb < 8; nb++)
      orow[c + 16*nb] = oacc[nb][i];
  }
}

// ------------------------------------------------------------------
// merge k-split partials: O = sum_s e^{m_s-m} O_s / sum_s e^{m_s-m} l_s
// ------------------------------------------------------------------
__global__ __launch_bounds__(128) void attn_merge(const float* __restrict__ Opart,
    const float* __restrict__ mlpart, f16* __restrict__ ah){
  int bid = blockIdx.x;
  int tid = threadIdx.x;
  int row = tid & 31, d0 = (tid >> 5) * 32;
  float ms[NS_], lv[NS_], wgt[NS_];
  float m = -3e38f;
  #pragma unroll
  for (int s = 0; s < NS_; s++){
    size_t base = ((size_t)(s*256 + bid)*32 + row);
    ms[s] = mlpart[base*2];
    lv[s] = mlpart[base*2 + 1];
    m = fmaxf(m, ms[s]);
  }
  float wsum = 0.f;
  #pragma unroll
  for (int s = 0; s < NS_; s++){ wgt[s] = __expf(ms[s] - m); wsum += wgt[s]*lv[s]; }
  float inv = 1.f / wsum;
  int token = (bid >> 6)*T_ + (bid & 63)*32 + row;
  #pragma unroll
  for (int dd = 0; dd < 32; dd += 4){
    f32x4 o = (f32x4){0,0,0,0};
    #pragma unroll
    for (int s = 0; s < NS_; s++){
      f32x4 p = *(const f32x4*)&Opart[(((size_t)(s*256 + bid)*32 + row))*128 + d0 + dd];
      o[0] += wgt[s]*p[0]; o[1] += wgt[s]*p[1]; o[2] += wgt[s]*p[2]; o[3] += wgt[s]*p[3];
    }
    f16x4 h;
    h[0]=(f16)(o[0]*inv); h[1]=(f16)(o[1]*inv); h[2]=(f16)(o[2]*inv); h[3]=(f16)(o[3]*inv);
    *(f16x4*)&ah[(size_t)token*H_ + d0 + dd] = h;
  }
}

// ------------------------------------------------------------------
// grouped O GEMM v2 (unchanged): tile-list driven, K=128 single stage
// ------------------------------------------------------------------
#define LDT 136
__global__ __launch_bounds__(256) void o_gemm(const f16* __restrict__ ah,
    const f16* __restrict__ oT, const int* __restrict__ cnt,
    const int* __restrict__ list, const float* __restrict__ listw,
    const int* __restrict__ tlist, const int* __restrict__ ntile,
    float* __restrict__ out){
  __shared__ __align__(16) f16 a_s[64*LDT];
  __shared__ __align__(16) f16 b_s[128*LDT];
  __shared__ int tok_s[64];
  __shared__ float wgt_s[64];
  int nitems = (*ntile) * 16;
  int tid = threadIdx.x;
  int l = tid & 63, wv = tid >> 6;
  int wm = wv >> 1, wn = wv & 1;
  int g = l >> 4, c = l & 15;
  for (int w = blockIdx.x; w < nitems; w += gridDim.x){
    int tile = w >> 4, nbt = w & 15;
    int ent = tlist[tile];
    int e = ent >> 8, mt = ent & 255;
    int ce = cnt[e];
    int m0 = mt * 64, n0 = nbt * 128;
    if (tid < 64){
      int gr = m0 + tid;
      tok_s[tid] = (gr < ce) ? list[e*N_TOK + gr] : 0;
      wgt_s[tid] = (gr < ce) ? listw[e*N_TOK + gr] : 0.f;
    }
    __syncthreads();
    #pragma unroll
    for (int i = 0; i < 4; i++){
      int s = tid + 256*i;
      int r = s >> 4, cs = (s & 15)*8;
      f16x8 v = *(const f16x8*)&ah[(size_t)tok_s[r]*H_ + cs];
      float wgt = wgt_s[r];
      f16x8 o;
      #pragma unroll
      for (int j = 0; j < 8; j++) o[j] = (f16)((float)v[j]*wgt);
      *(f16x8*)&a_s[r*LDT + cs] = o;
    }
    #pragma unroll
    for (int i = 0; i < 8; i++){
      int s = tid + 256*i;
      int j = s >> 4, cs = (s & 15)*8;
      f16x8 v = *(const f16x8*)&oT[((size_t)e*C_ + n0 + j)*H_ + cs];
      *(f16x8*)&b_s[j*LDT + cs] = v;
    }
    __syncthreads();
    f32x4 acc[2][4];
    #pragma unroll
    for (int m = 0; m < 2; m++)
      #pragma unroll
      for (int n = 0; n < 4; n++) acc[m][n] = (f32x4){0.f,0.f,0.f,0.f};
    #pragma unroll
    for (int ks = 0; ks < 4; ks++){
      f16x8 af[2], bf[4];
      #pragma unroll
      for (int m = 0; m < 2; m++)
        af[m] = *(const f16x8*)&a_s[(wm*32 + m*16 + c)*LDT + ks*32 + 8*g];
      #pragma unroll
      for (int n = 0; n < 4; n++)
        bf[n] = *(const f16x8*)&b_s[(wn*64 + n*16 + c)*LDT + ks*32 + 8*g];
      #pragma unroll
      for (int m = 0; m < 2; m++)
        #pragma unroll
        for (int n = 0; n < 4; n++)
          acc[m][n] = MFMA(af[m], bf[n], acc[m][n]);
    }
    #pragma unroll
    for (int m = 0; m < 2; m++){
      #pragma unroll
      for (int i = 0; i < 4; i++){
        int row = wm*32 + m*16 + 4*g + i;
        int gr = m0 + row;
        if (gr < ce){
          int tok = tok_s[row];
          #pragma unroll
          for (int n = 0; n < 4; n++){
            int col = n0 + wn*64 + n*16 + c;
            atomicAdd(&out[(size_t)tok*C_ + col], acc[m][n][i]);
          }
        }
      }
    }
    __syncthreads();
  }
}

// ------------------------------------------------------------------
extern "C" void kernel_launch(void* const* d_in, const int* in_sizes, int n_in,
                              void* d_out, int out_size, void* d_ws, size_t ws_size,
                              hipStream_t stream){
  const float* hs    = (const float*)d_in[0];
  const int*   pos   = (const int*)d_in[1];
  const float* sim   = (const float*)d_in[2];
  const float* gates = (const float*)d_in[3];
  const float* qp    = (const float*)d_in[4];
  const float* kp    = (const float*)d_in[5];
  const float* vp    = (const float*)d_in[6];
  const float* op    = (const float*)d_in[7];
  float* out = (float*)d_out;
  char* ws = (char*)d_ws;
  // workspace layout (extent 89137664, unchanged)
  int*    cnt    = (int*)(ws + 0);               // 16 int
  int*    ntile  = (int*)(ws + 64);              // 1 int
  double* wninv  = (double*)(ws + 128);          // 16 f64
  double* sigg   = (double*)(ws + 256);          // 16 f64
  int*    tlist  = (int*)(ws + 512);             // 2048 int (64-gran)
  int*    list   = (int*)(ws + 8704);            // 16*8192 int
  float*  listw  = (float*)(ws + 532992);        // 16*8192 f32
  f16*    xh     = (f16*)(ws + 1057280);         // [8192][2048] (dead after qkv_gemm)
  float*  Opart  = (float*)(ws + 1057280);       // overlays xh: [4][256][32][128] f32
  float*  mlpart = (float*)(ws + 17834496);      // overlays xh: [4][256][32][2] f32
  f16*    wT     = (f16*)(ws + 34611712);        // [16][384][2048]
  f16*    oT     = (f16*)(ws + 59777536);        // [16][2048][128]
  float*  qkv    = (float*)(ws + 68166144);      // [8192][384] f32
  double* dpart  = (double*)(ws + 68166144);     // overlays qkv: [4][8192][17] f64 (dead before qkv memset)
  f16*    ah     = (f16*)(ws + 68166144);        // overlays qkv (dead after rope)
  f16*    qh     = (f16*)(ws + 80749056);        // [8192][128]
  f16*    kh     = (f16*)(ws + 82846208);
  f16*    vh     = (f16*)(ws + 84943360);
  int*    tlist2 = (int*)(ws + 87040512);        // 1024 int (128-gran)
  int*    ntile2 = (int*)(ws + 87044608);        // 1 int

  hipMemsetAsync(cnt, 0, 64, stream);
  hipMemsetAsync(out, 0, (size_t)N_TOK*C_*4, stream);

  prep_kernel<<<1, 256, 0, stream>>>(sim, gates, wninv, sigg);
  conv_x<<<4096, 256, 0, stream>>>(hs, xh);
  conv_w<<<dim3(32, 2, 48), 256, 0, stream>>>(qp, kp, vp, wT);
  conv_o<<<dim3(32, 2, 16), 256, 0, stream>>>(op, oT);
  gate_dot<<<dim3(256, NS_), 256, 0, stream>>>(hs, sim, dpart);
  gate_route<<<32, 256, 0, stream>>>(dpart, wninv, sigg, cnt, list, listw);
  tile_builder<<<1, 64, 0, stream>>>(cnt, tlist, ntile, tlist2, ntile2);
  // qkv memset AFTER gate_route: dpart overlays qkv and is dead now
  hipMemsetAsync(qkv, 0, (size_t)N_TOK*384*4, stream);
  qkv_gemm<<<512, 256, 0, stream>>>(xh, wT, cnt, list, listw, tlist2, ntile2, qkv);
  rope_kernel<<<N_TOK, 192, 0, stream>>>(qkv, pos, qh, kh, vh);
  attn_kernel<<<dim3(256, NS_), 128, 0, stream>>>(qh, kh, vh, Opart, mlpart);
  attn_merge<<<256, 128, 0, stream>>>(Opart, mlpart, ah);
  o_gemm<<<2048, 256, 0, stream>>>(ah, oT, cnt, list, listw, tlist, ntile, out);
}